// Round 3
// baseline (76.712 us; speedup 1.0000x reference)
//
#include <hip/hip_runtime.h>

#define D 16
#define OUTD 153                 // 1 + 16 + 16 + 120
#define TILE_ROWS 64
#define THREADS 256
#define NBLOCKS 1024             // 4 blocks/CU * 256 CUs: fully resident (38.25 KiB LDS * 4 = 153 KiB)

// Emit columns [LO, HI) of one output row into dst (LDS), fully unrolled.
template<int LO, int HI>
__device__ __forceinline__ void emit_cols(const float xv[D], float* dst) {
    if (LO <= 0 && 0 < HI) dst[0] = 1.0f;
#pragma unroll
    for (int k = 0; k < D; ++k) {
        const int c1 = 1 + k;                    // x / 16^0.25
        if (c1 >= LO && c1 < HI) dst[c1] = xv[k] * 0.5f;
        const int c2 = 17 + k;                   // x^2 / (4*sqrt(2))
        if (c2 >= LO && c2 < HI) dst[c2] = xv[k] * xv[k] * 0.17677669529663687f;
    }
#pragma unroll
    for (int i = 0; i < D; ++i) {
#pragma unroll
        for (int j = i + 1; j < D; ++j) {        // x_i*x_j / 4
            const int c = 33 + (15 * i - (i * (i - 1)) / 2) + (j - i - 1);
            if (c >= LO && c < HI) dst[c] = xv[i] * xv[j] * 0.25f;
        }
    }
}

__device__ __forceinline__ void load_tile(const float* __restrict__ x, int nrows,
                                          int t, int ntiles, int r, float (&dstv)[D]) {
    const int row = t * TILE_ROWS + r;
    if (t < ntiles && row < nrows) {
        const float4* xrow = reinterpret_cast<const float4*>(x + (size_t)row * D);
#pragma unroll
        for (int m = 0; m < 4; ++m) {
            float4 v = xrow[m];
            dstv[4 * m + 0] = v.x; dstv[4 * m + 1] = v.y;
            dstv[4 * m + 2] = v.z; dstv[4 * m + 3] = v.w;
        }
    }
}

__device__ __forceinline__ void tile_body(const float* __restrict__ x,
                                          float* __restrict__ out, float* olds,
                                          int nrows, int ntiles, int t, int tnext,
                                          int tid, int q, int r,
                                          const float (&xv)[D], float (&nxv)[D]) {
    const int r0 = t * TILE_ROWS;

    // Phase 1: emit this tile into LDS (flat 64x153, row stride 153 = odd -> 2-way bank alias, free)
    if (r0 + r < nrows) {
        float* dst = olds + r * OUTD;
        if      (q == 0) emit_cols<0,   39 >(xv, dst);
        else if (q == 1) emit_cols<39,  77 >(xv, dst);
        else if (q == 2) emit_cols<77,  115>(xv, dst);
        else             emit_cols<115, 153>(xv, dst);
    }
    __syncthreads();   // drain is cheap here: vmem queue is ~empty at this point

    // Phase 2a: issue next tile's x prefetch (consumed only in NEXT tile's emit)
    load_tile(x, nrows, tnext, ntiles, r, nxv);

    // Phase 2b: stream this tile's output, flat coalesced float4
    const int nrow_blk = min(TILE_ROWS, nrows - r0);
    const int nelem = nrow_blk * OUTD;
    const int nf4 = nelem >> 2;
    float4* gout = reinterpret_cast<float4*>(out + (size_t)r0 * OUTD);  // 39168B * t: 16B-aligned
    const float4* lsrc = reinterpret_cast<const float4*>(olds);
    for (int g = tid; g < nf4; g += THREADS) gout[g] = lsrc[g];
    if (tid < (nelem & 3)) out[(size_t)r0 * OUTD + nf4 * 4 + tid] = olds[nf4 * 4 + tid];

    // Raw barrier: do NOT drain vmcnt -- stores + prefetch loads stay in flight.
    // LDS-reuse safe: every ds_read was lgkm-waited before its dependent store issued,
    // so reaching this barrier means all waves are done reading olds.
    asm volatile("" ::: "memory");
    __builtin_amdgcn_sched_barrier(0);
    __builtin_amdgcn_s_barrier();
    __builtin_amdgcn_sched_barrier(0);
    asm volatile("" ::: "memory");
}

__global__ __launch_bounds__(THREADS) void taylor_fm_kernel(const float* __restrict__ x,
                                                            float* __restrict__ out,
                                                            int nrows) {
    __shared__ float olds[TILE_ROWS * OUTD];   // 38.25 KiB
    const int tid = threadIdx.x;
    const int q   = tid >> 6;                  // wave id (uniform)
    const int r   = tid & 63;                  // row within tile
    const int ntiles = (nrows + TILE_ROWS - 1) / TILE_ROWS;
    const int stride = gridDim.x;

    float xva[D], xvb[D];
    int t = blockIdx.x;
    load_tile(x, nrows, t, ntiles, r, xva);

    // 2x-unrolled ping-pong: prefetched regs are first used one full tile later
    for (; t < ntiles; t += 2 * stride) {
        tile_body(x, out, olds, nrows, ntiles, t, t + stride, tid, q, r, xva, xvb);
        if (t + stride < ntiles)
            tile_body(x, out, olds, nrows, ntiles, t + stride, t + 2 * stride, tid, q, r, xvb, xva);
    }
}

extern "C" void kernel_launch(void* const* d_in, const int* in_sizes, int n_in,
                              void* d_out, int out_size, void* d_ws, size_t ws_size,
                              hipStream_t stream) {
    const float* x = (const float*)d_in[0];
    float* out = (float*)d_out;
    const int nrows = in_sizes[0] / D;         // 4*16*8192 = 524288
    const int ntiles = (nrows + TILE_ROWS - 1) / TILE_ROWS;
    const int blocks = ntiles < NBLOCKS ? ntiles : NBLOCKS;
    taylor_fm_kernel<<<blocks, THREADS, 0, stream>>>(x, out, nrows);
}

// Round 4
// 67.799 us; speedup vs baseline: 1.1315x; 1.1315x over previous
//
#include <hip/hip_runtime.h>

#define D 16
#define OUTD 153                 // 1 + 16 + 16 + 120
#define TILE_ROWS 32
#define THREADS 256

// Emit columns [LO, HI) of one output row into dst (LDS), fully unrolled.
// All indices/scales fold to compile-time constants; xv[] stays in registers.
template<int LO, int HI>
__device__ __forceinline__ void emit_cols(const float xv[D], float* dst) {
    if (LO <= 0 && 0 < HI) dst[0] = 1.0f;
#pragma unroll
    for (int k = 0; k < D; ++k) {
        const int c1 = 1 + k;                    // x / 16^0.25
        if (c1 >= LO && c1 < HI) dst[c1] = xv[k] * 0.5f;
        const int c2 = 17 + k;                   // x^2 / (4*sqrt(2))
        if (c2 >= LO && c2 < HI) dst[c2] = xv[k] * xv[k] * 0.17677669529663687f;
    }
#pragma unroll
    for (int i = 0; i < D; ++i) {
#pragma unroll
        for (int j = i + 1; j < D; ++j) {        // x_i*x_j / 4
            const int c = 33 + (15 * i - (i * (i - 1)) / 2) + (j - i - 1);
            if (c >= LO && c < HI) dst[c] = xv[i] * xv[j] * 0.25f;
        }
    }
}

__global__ __launch_bounds__(THREADS) void taylor_fm_kernel(const float* __restrict__ x,
                                                            float* __restrict__ out,
                                                            int nrows) {
    __shared__ float olds[TILE_ROWS * OUTD];     // 19.125 KiB -> 8 blocks/CU, 32 waves/CU
    const int tid = threadIdx.x;
    const int r   = tid & 31;                    // row within tile (8 threads per row)
    const int r8  = tid >> 5;                    // col-range id (uniform per half-wave)
    const int r0  = blockIdx.x * TILE_ROWS;
    const int row = r0 + r;

    if (row < nrows) {
        // Full row into registers (8 threads share a row -> L1 hits)
        const float4* xrow = reinterpret_cast<const float4*>(x + (size_t)row * D);
        float xv[D];
#pragma unroll
        for (int m = 0; m < 4; ++m) {
            float4 v = xrow[m];
            xv[4 * m + 0] = v.x; xv[4 * m + 1] = v.y;
            xv[4 * m + 2] = v.z; xv[4 * m + 3] = v.w;
        }
        // Emit: bank pattern (25*r + c) % 32 over r=0..31 is bijective -> conflict-free
        float* dst = olds + r * OUTD;
        switch (r8) {                            // 8 ranges of ~19 cols
            case 0: emit_cols<0,   20 >(xv, dst); break;
            case 1: emit_cols<20,  39 >(xv, dst); break;
            case 2: emit_cols<39,  58 >(xv, dst); break;
            case 3: emit_cols<58,  77 >(xv, dst); break;
            case 4: emit_cols<77,  96 >(xv, dst); break;
            case 5: emit_cols<96,  115>(xv, dst); break;
            case 6: emit_cols<115, 134>(xv, dst); break;
            case 7: emit_cols<134, 153>(xv, dst); break;
        }
    }
    __syncthreads();

    // Stream the tile's output chunk: flat, fully coalesced float4 stores.
    // Block chunk = 32*153*4 = 19584 B (16B-aligned), nelem = 4896 (mult of 4).
    const int nrow_blk = min(TILE_ROWS, nrows - r0);
    const int nelem = nrow_blk * OUTD;
    const int nf4 = nelem >> 2;
    float4* gout = reinterpret_cast<float4*>(out + (size_t)r0 * OUTD);
    const float4* lsrc = reinterpret_cast<const float4*>(olds);
    for (int g = tid; g < nf4; g += THREADS) gout[g] = lsrc[g];
    if (tid < (nelem & 3)) out[(size_t)r0 * OUTD + nf4 * 4 + tid] = olds[nf4 * 4 + tid];
}

extern "C" void kernel_launch(void* const* d_in, const int* in_sizes, int n_in,
                              void* d_out, int out_size, void* d_ws, size_t ws_size,
                              hipStream_t stream) {
    const float* x = (const float*)d_in[0];
    float* out = (float*)d_out;
    const int nrows = in_sizes[0] / D;           // 4*16*8192 = 524288
    const int blocks = (nrows + TILE_ROWS - 1) / TILE_ROWS;   // 16384
    taylor_fm_kernel<<<blocks, THREADS, 0, stream>>>(x, out, nrows);
}